// Round 7
// baseline (229.884 us; speedup 1.0000x reference)
//
#include <hip/hip_runtime.h>

#define N_NODES  100000
#define N_EDGES  3200000
#define N_GRAPHS 512
#define F_IN     5
#define F_HID    16

#define PBLK   512                      // k_part block size
#define CHUNK  4096                     // edges per k_part workgroup
#define NCHUNK ((N_EDGES + CHUNK - 1) / CHUNK)          // 782
#define BKT_NODES 256                   // nodes per coarse bucket
#define NBKT ((N_NODES + BKT_NODES - 1) / BKT_NODES)    // 391
#define CAP 10240                       // mean 8184, +22 sigma

// ---------------- helpers ----------------

__device__ inline unsigned short f2bf(float f) {
    unsigned u = __float_as_uint(f);
    return (unsigned short)((u + 0x7fffu + ((u >> 16) & 1u)) >> 16);   // RNE
}
__device__ inline float bf2f(unsigned short h) {
    return __uint_as_float(((unsigned)h) << 16);
}
__device__ inline float4 cvt4(ushort4 u) {
    return make_float4(bf2f(u.x), bf2f(u.y), bf2f(u.z), bf2f(u.w));
}

// block-wide inclusive scan via wave shfl; NW = number of waves (<=8)
template <int NW>
__device__ inline int block_incl_scan(int v, int t, int* wsum) {
    int lane = t & 63, wave = t >> 6;
    int x = v;
#pragma unroll
    for (int o = 1; o < 64; o <<= 1) {
        int y = __shfl_up(x, o, 64);
        if (lane >= o) x += y;
    }
    if (lane == 63) wsum[wave] = x;
    __syncthreads();
    if (t < 64) {
        int w = (t < NW) ? wsum[t] : 0;
#pragma unroll
        for (int o = 1; o < NW; o <<= 1) {
            int y = __shfl_up(w, o, 64);
            if (t >= o) w += y;
        }
        if (t < NW) wsum[t] = w;
    }
    __syncthreads();
    return x + (wave ? wsum[wave - 1] : 0);
}

// ---------------- kernels ----------------

__global__ void k_zero(int* __restrict__ cursor, float* __restrict__ out,
                       float* __restrict__ cnt) {
    int i = blockIdx.x * blockDim.x + threadIdx.x;
    if (i < NBKT) cursor[i] = 0;
    if (i < N_GRAPHS * F_HID) out[i] = 0.0f;
    if (i < N_GRAPHS) cnt[i] = 0.0f;
}

// staged counting-sort partition into 391 coarse buckets of dst>>8.
// one global atomic per (bucket, workgroup); direct rank-addressed writes
// (frontier = 391 L2-resident bucket tips; lines fill before eviction).
__global__ __launch_bounds__(PBLK) void k_part(const int* __restrict__ src,
                                               const int* __restrict__ dst,
                                               int* __restrict__ cursor,
                                               unsigned* __restrict__ packed) {
    __shared__ int hist[PBLK];
    __shared__ int scn[PBLK];
    __shared__ int rnk[PBLK];
    __shared__ int gbase[PBLK];
    __shared__ int wsum[8];
    int t = threadIdx.x;
    int chunk0 = blockIdx.x * CHUNK;
    int n = min(CHUNK, N_EDGES - chunk0);
    hist[t] = 0;
    __syncthreads();
    int ls[CHUNK / PBLK], ld[CHUNK / PBLK];
    for (int k = t, idx = 0; k < n; k += PBLK, idx++) {
        ls[idx] = src[chunk0 + k];
        ld[idx] = dst[chunk0 + k];
        atomicAdd(&hist[ld[idx] >> 8], 1);
    }
    __syncthreads();
    int v = hist[t];
    int incl = block_incl_scan<8>(v, t, wsum);
    int excl = incl - v;
    scn[t] = excl;
    rnk[t] = excl;
    gbase[t] = (v > 0) ? atomicAdd(&cursor[t], v) : 0;
    __syncthreads();
    for (int k = t, idx = 0; k < n; k += PBLK, idx++) {
        int d = ld[idx], s = ls[idx];
        int b = d >> 8;
        int r = atomicAdd(&rnk[b], 1);
        int g = gbase[b] + (r - scn[b]);
        if (g < CAP)
            packed[(size_t)b * CAP + g] = ((unsigned)s << 8) | (unsigned)(d & 255);
    }
}

// parallel exclusive scan of 391 bucket counts -> bktBase
__global__ __launch_bounds__(512) void k_scanb(const int* __restrict__ cursor,
                                               int* __restrict__ bktBase) {
    __shared__ int wsum[8];
    int t = threadIdx.x;
    int v = (t < NBKT) ? min(cursor[t], CAP) : 0;
    int incl = block_incl_scan<8>(v, t, wsum);
    if (t < NBKT) bktBase[t] = incl - v;
    if (t == NBKT - 1) bktBase[NBKT] = incl;
}

// per coarse bucket: node-level counting sort -> CSR col + row_ptr + dinv,
// fused with layer-1 transform: pb = bf16((x @ W1) * dinv) for this bucket's nodes
__global__ __launch_bounds__(512) void k_csr(const int* __restrict__ cursor,
                                             const int* __restrict__ bktBase,
                                             const unsigned* __restrict__ packed,
                                             const float* __restrict__ x,
                                             const float* __restrict__ W1,
                                             int* __restrict__ row_ptr,
                                             int* __restrict__ col,
                                             float* __restrict__ dinv,
                                             unsigned short* __restrict__ pb) {
    __shared__ int hist[BKT_NODES];
    __shared__ int rnk[BKT_NODES];
    __shared__ int wsum[8];
    __shared__ float w1[F_IN * F_HID];
    int b = blockIdx.x, t = threadIdx.x;
    int n = min(cursor[b], CAP);
    int base = bktBase[b];
    if (t < BKT_NODES) hist[t] = 0;
    if (t >= 512 - F_IN * F_HID) w1[t - (512 - F_IN * F_HID)] = W1[t - (512 - F_IN * F_HID)];
    __syncthreads();
    const unsigned* pk = packed + (size_t)b * CAP;
    for (int k = t; k < n; k += 512)
        atomicAdd(&hist[pk[k] & 255], 1);
    __syncthreads();
    int v = (t < BKT_NODES) ? hist[t] : 0;
    int incl = block_incl_scan<8>(v, t, wsum);
    int excl = incl - v;
    if (t < BKT_NODES) rnk[t] = excl;
    __syncthreads();
    for (int k = t; k < n; k += 512) {
        unsigned w = pk[k];
        int r = atomicAdd(&rnk[w & 255], 1);
        col[base + r] = (int)(w >> 8);
    }
    // fused per-node work for this bucket's 256 nodes
    if (t < BKT_NODES) {
        int node = b * BKT_NODES + t;
        if (node < N_NODES) {
            row_ptr[node] = base + excl;
            float di = rsqrtf((float)(1 + v));
            dinv[node] = di;
            if (node == N_NODES - 1) row_ptr[N_NODES] = base + excl + v;
            float xi[F_IN];
#pragma unroll
            for (int k = 0; k < F_IN; k++) xi[k] = x[node * F_IN + k];
            float hv[F_HID];
#pragma unroll
            for (int c = 0; c < F_HID; c++) {
                float h = 0.0f;
#pragma unroll
                for (int k = 0; k < F_IN; k++) h += xi[k] * w1[k * F_HID + c];
                hv[c] = h * di;
            }
            unsigned pkk[8];
#pragma unroll
            for (int q = 0; q < 8; q++)
                pkk[q] = (unsigned)f2bf(hv[2 * q]) | ((unsigned)f2bf(hv[2 * q + 1]) << 16);
            uint4* d4 = (uint4*)(pb + (size_t)node * F_HID);
            d4[0] = make_uint4(pkk[0], pkk[1], pkk[2], pkk[3]);
            d4[1] = make_uint4(pkk[4], pkk[5], pkk[6], pkk[7]);
        }
    }
}

// pull: S[i] = pb[i] + sum over row of pb[col[k]]; 4 threads/node, fp32 acc
__global__ void k_pull(const int* __restrict__ row_ptr, const int* __restrict__ col,
                       const unsigned short* __restrict__ pb, float* __restrict__ S) {
    int t = blockIdx.x * blockDim.x + threadIdx.x;
    int i = t >> 2;
    int j = t & 3;
    if (i >= N_NODES) return;
    int beg = row_ptr[i], end = row_ptr[i + 1];
    const ushort4* pb4 = (const ushort4*)pb;
    float4 acc = cvt4(pb4[i * 4 + j]);                // self loop
    int k = beg;
    for (; k + 3 < end; k += 4) {
        int s0 = col[k], s1 = col[k + 1], s2 = col[k + 2], s3 = col[k + 3];
        ushort4 a = pb4[s0 * 4 + j];
        ushort4 b = pb4[s1 * 4 + j];
        ushort4 c = pb4[s2 * 4 + j];
        ushort4 d = pb4[s3 * 4 + j];
        float4 fa = cvt4(a), fb = cvt4(b), fc = cvt4(c), fd = cvt4(d);
        acc.x += fa.x + fb.x + fc.x + fd.x;
        acc.y += fa.y + fb.y + fc.y + fd.y;
        acc.z += fa.z + fb.z + fc.z + fd.z;
        acc.w += fa.w + fb.w + fc.w + fd.w;
    }
    for (; k < end; k++) {
        float4 f = cvt4(pb4[col[k] * 4 + j]);
        acc.x += f.x; acc.y += f.y; acc.z += f.z; acc.w += f.w;
    }
    ((float4*)S)[i * 4 + j] = acc;
}

// finalize layer1: h1 = relu(dinv*S + b1); pb = bf16((h1 @ W2) * dinv)
__global__ void k_mid(const float* __restrict__ W2, const float* __restrict__ b1,
                      const float* __restrict__ dinv, const float* __restrict__ S,
                      unsigned short* __restrict__ pb) {
    __shared__ float w[F_HID * F_HID];
    __shared__ float bb[F_HID];
    int t = threadIdx.x;
    if (t < F_HID * F_HID) w[t] = W2[t];
    if (t < F_HID) bb[t] = b1[t];
    __syncthreads();
    int i = blockIdx.x * blockDim.x + t;
    if (i >= N_NODES) return;
    float di = dinv[i];
    float h[F_HID];
#pragma unroll
    for (int c = 0; c < F_HID; c++) {
        float v = di * S[i * F_HID + c] + bb[c];
        h[c] = v > 0.0f ? v : 0.0f;
    }
    float hv[F_HID];
#pragma unroll
    for (int c2 = 0; c2 < F_HID; c2++) {
        float m = 0.0f;
#pragma unroll
        for (int c = 0; c < F_HID; c++) m += h[c] * w[c * F_HID + c2];
        hv[c2] = m * di;
    }
    unsigned pk[8];
#pragma unroll
    for (int q = 0; q < 8; q++)
        pk[q] = (unsigned)f2bf(hv[2 * q]) | ((unsigned)f2bf(hv[2 * q + 1]) << 16);
    uint4* d4 = (uint4*)(pb + (size_t)i * F_HID);
    d4[0] = make_uint4(pk[0], pk[1], pk[2], pk[3]);
    d4[1] = make_uint4(pk[4], pk[5], pk[6], pk[7]);
}

// finalize layer2 + pool; batch sorted -> LDS per-graph accumulation
__global__ void k_pool(const float* __restrict__ b2, const float* __restrict__ dinv,
                       const float* __restrict__ S, const int* __restrict__ batch,
                       float* __restrict__ out, float* __restrict__ cnt) {
    __shared__ float bb[F_HID];
    __shared__ float acc[16][F_HID];
    __shared__ int gcnt[16];
    __shared__ int g0s;
    int t = threadIdx.x;
    if (t < F_HID) bb[t] = b2[t];
    if (t < 16) gcnt[t] = 0;
    for (int i2 = t; i2 < 16 * F_HID; i2 += 256) ((float*)acc)[i2] = 0.0f;
    int blk0 = blockIdx.x * 256;
    if (t == 0) g0s = batch[blk0 < N_NODES ? blk0 : N_NODES - 1];
    __syncthreads();
    int g0 = g0s;
    int i = blk0 + t;
    if (i < N_NODES) {
        float di = dinv[i];
        int g = batch[i];
        int l = g - g0;
        float h[F_HID];
#pragma unroll
        for (int c = 0; c < F_HID; c++) {
            float v = di * S[i * F_HID + c] + bb[c];
            h[c] = v > 0.0f ? v : 0.0f;
        }
        if (l >= 0 && l < 16) {
#pragma unroll
            for (int c = 0; c < F_HID; c++) atomicAdd(&acc[l][c], h[c]);
            atomicAdd(&gcnt[l], 1);
        } else {
#pragma unroll
            for (int c = 0; c < F_HID; c++) atomicAdd(&out[g * F_HID + c], h[c]);
            atomicAdd(&cnt[g], 1.0f);
        }
    }
    __syncthreads();
    {
        int l = t >> 4, c = t & 15;
        if (gcnt[l] > 0) atomicAdd(&out[(g0 + l) * F_HID + c], acc[l][c]);
    }
    if (t < 16 && gcnt[t] > 0) atomicAdd(&cnt[g0 + t], (float)gcnt[t]);
}

__global__ void k_div(float* __restrict__ out, const float* __restrict__ cnt) {
    int i = blockIdx.x * blockDim.x + threadIdx.x;
    if (i < N_GRAPHS * F_HID) {
        float c = cnt[i / F_HID];
        out[i] /= fmaxf(c, 1.0f);
    }
}

// ---------------- launcher ----------------

extern "C" void kernel_launch(void* const* d_in, const int* in_sizes, int n_in,
                              void* d_out, int out_size, void* d_ws, size_t ws_size,
                              hipStream_t stream) {
    const float* x     = (const float*)d_in[0];
    const int*   ei    = (const int*)d_in[1];   // [2, N_EDGES]
    const int*   batch = (const int*)d_in[2];
    const float* W1    = (const float*)d_in[3];
    const float* b1    = (const float*)d_in[4];
    const float* W2    = (const float*)d_in[5];
    const float* b2    = (const float*)d_in[6];
    float* out = (float*)d_out;

    int*            cursor  = (int*)d_ws;                                  // 512
    int*            bktBase = cursor + 512;                                // 512
    unsigned*       packed  = (unsigned*)(bktBase + 512);                  // NBKT*CAP
    int*            row_ptr = (int*)(packed + (size_t)NBKT * CAP);         // 100352
    int*            col     = row_ptr + 100352;                            // N_EDGES
    float*          dinv    = (float*)(col + N_EDGES);                     // N
    unsigned short* pb      = (unsigned short*)(dinv + N_NODES);           // 16N ushort
    float*          S       = (float*)(pb + (size_t)N_NODES * F_HID);      // 16N
    float*          cnt     = S + (size_t)N_NODES * F_HID;                 // 512

    const int* src = ei;
    const int* dst = ei + N_EDGES;

    const int nb_nodes = (N_NODES + 255) / 256;
    const int nb_pull  = (N_NODES * 4 + 255) / 256;

    k_zero<<<(N_GRAPHS * F_HID + 255) / 256, 256, 0, stream>>>(cursor, out, cnt);
    k_part<<<NCHUNK, PBLK, 0, stream>>>(src, dst, cursor, packed);
    k_scanb<<<1, 512, 0, stream>>>(cursor, bktBase);
    k_csr<<<NBKT, 512, 0, stream>>>(cursor, bktBase, packed, x, W1,
                                    row_ptr, col, dinv, pb);
    k_pull<<<nb_pull, 256, 0, stream>>>(row_ptr, col, pb, S);
    k_mid<<<nb_nodes, 256, 0, stream>>>(W2, b1, dinv, S, pb);
    k_pull<<<nb_pull, 256, 0, stream>>>(row_ptr, col, pb, S);
    k_pool<<<nb_nodes, 256, 0, stream>>>(b2, dinv, S, batch, out, cnt);
    k_div<<<(N_GRAPHS * F_HID + 255) / 256, 256, 0, stream>>>(out, cnt);
}

// Round 8
// 201.788 us; speedup vs baseline: 1.1392x; 1.1392x over previous
//
#include <hip/hip_runtime.h>

#define N_NODES  100000
#define N_EDGES  3200000
#define N_GRAPHS 512
#define F_IN     5
#define F_HID    16

#define PBLK   512                      // k_part block size
#define CHUNK  8192                     // edges per k_part workgroup
#define NCHUNK ((N_EDGES + CHUNK - 1) / CHUNK)          // 391
#define BKT_NODES 256                   // nodes per coarse bucket
#define NBKT ((N_NODES + BKT_NODES - 1) / BKT_NODES)    // 391
#define CAP 10240                       // mean 8184, +22 sigma

// ---------------- helpers ----------------

__device__ inline unsigned short f2bf(float f) {
    unsigned u = __float_as_uint(f);
    return (unsigned short)((u + 0x7fffu + ((u >> 16) & 1u)) >> 16);   // RNE
}
__device__ inline float bf2f(unsigned short h) {
    return __uint_as_float(((unsigned)h) << 16);
}
__device__ inline float4 cvt4(ushort4 u) {
    return make_float4(bf2f(u.x), bf2f(u.y), bf2f(u.z), bf2f(u.w));
}
__device__ inline float4 shfl_xor4(float4 v, int m) {
    return make_float4(__shfl_xor(v.x, m, 64), __shfl_xor(v.y, m, 64),
                       __shfl_xor(v.z, m, 64), __shfl_xor(v.w, m, 64));
}

// block-wide inclusive scan via wave shfl; NW = number of waves (<=8)
template <int NW>
__device__ inline int block_incl_scan(int v, int t, int* wsum) {
    int lane = t & 63, wave = t >> 6;
    int x = v;
#pragma unroll
    for (int o = 1; o < 64; o <<= 1) {
        int y = __shfl_up(x, o, 64);
        if (lane >= o) x += y;
    }
    if (lane == 63) wsum[wave] = x;
    __syncthreads();
    if (t < 64) {
        int w = (t < NW) ? wsum[t] : 0;
#pragma unroll
        for (int o = 1; o < NW; o <<= 1) {
            int y = __shfl_up(w, o, 64);
            if (t >= o) w += y;
        }
        if (t < NW) wsum[t] = w;
    }
    __syncthreads();
    return x + (wave ? wsum[wave - 1] : 0);
}

// per-thread gather-accumulate over one CSR row slice (channels 4j..4j+3)
__device__ inline float4 row_gather(const ushort4* __restrict__ pb4, int i, int j,
                                    int beg, int end, const int* __restrict__ col) {
    float4 acc = cvt4(pb4[i * 4 + j]);                // self loop
    int k = beg;
    for (; k + 3 < end; k += 4) {
        int s0 = col[k], s1 = col[k + 1], s2 = col[k + 2], s3 = col[k + 3];
        ushort4 a = pb4[s0 * 4 + j];
        ushort4 b = pb4[s1 * 4 + j];
        ushort4 c = pb4[s2 * 4 + j];
        ushort4 d = pb4[s3 * 4 + j];
        float4 fa = cvt4(a), fb = cvt4(b), fc = cvt4(c), fd = cvt4(d);
        acc.x += fa.x + fb.x + fc.x + fd.x;
        acc.y += fa.y + fb.y + fc.y + fd.y;
        acc.z += fa.z + fb.z + fc.z + fd.z;
        acc.w += fa.w + fb.w + fc.w + fd.w;
    }
    for (; k < end; k++) {
        float4 f = cvt4(pb4[col[k] * 4 + j]);
        acc.x += f.x; acc.y += f.y; acc.z += f.z; acc.w += f.w;
    }
    return acc;
}

// ---------------- kernels ----------------

__global__ void k_zero(int* __restrict__ cursor, float* __restrict__ out,
                       float* __restrict__ cnt) {
    int i = blockIdx.x * blockDim.x + threadIdx.x;
    if (i < NBKT) cursor[i] = 0;
    if (i < N_GRAPHS * F_HID) out[i] = 0.0f;
    if (i < N_GRAPHS) cnt[i] = 0.0f;
}

// staged counting-sort partition into 391 coarse buckets of dst>>8.
// one global atomic per (bucket, workgroup); direct rank-addressed writes.
__global__ __launch_bounds__(PBLK) void k_part(const int* __restrict__ src,
                                               const int* __restrict__ dst,
                                               int* __restrict__ cursor,
                                               unsigned* __restrict__ packed) {
    __shared__ int hist[PBLK];
    __shared__ int scn[PBLK];
    __shared__ int rnk[PBLK];
    __shared__ int gbase[PBLK];
    __shared__ int wsum[8];
    int t = threadIdx.x;
    int chunk0 = blockIdx.x * CHUNK;
    int n = min(CHUNK, N_EDGES - chunk0);
    hist[t] = 0;
    __syncthreads();
    int ls[CHUNK / PBLK], ld[CHUNK / PBLK];
    for (int k = t, idx = 0; k < n; k += PBLK, idx++) {
        ls[idx] = src[chunk0 + k];
        ld[idx] = dst[chunk0 + k];
        atomicAdd(&hist[ld[idx] >> 8], 1);
    }
    __syncthreads();
    int v = hist[t];
    int incl = block_incl_scan<8>(v, t, wsum);
    int excl = incl - v;
    scn[t] = excl;
    rnk[t] = excl;
    gbase[t] = (v > 0) ? atomicAdd(&cursor[t], v) : 0;
    __syncthreads();
    for (int k = t, idx = 0; k < n; k += PBLK, idx++) {
        int d = ld[idx], s = ls[idx];
        int b = d >> 8;
        int r = atomicAdd(&rnk[b], 1);
        int g = gbase[b] + (r - scn[b]);
        if (g < CAP)
            packed[(size_t)b * CAP + g] = ((unsigned)s << 8) | (unsigned)(d & 255);
    }
}

// parallel exclusive scan of 391 bucket counts -> bktBase
__global__ __launch_bounds__(512) void k_scanb(const int* __restrict__ cursor,
                                               int* __restrict__ bktBase) {
    __shared__ int wsum[8];
    int t = threadIdx.x;
    int v = (t < NBKT) ? min(cursor[t], CAP) : 0;
    int incl = block_incl_scan<8>(v, t, wsum);
    if (t < NBKT) bktBase[t] = incl - v;
    if (t == NBKT - 1) bktBase[NBKT] = incl;
}

// per coarse bucket: node-level counting sort -> CSR col + row_ptr + dinv,
// fused with layer-1 transform: pb = bf16((x @ W1) * dinv)
__global__ __launch_bounds__(512) void k_csr(const int* __restrict__ cursor,
                                             const int* __restrict__ bktBase,
                                             const unsigned* __restrict__ packed,
                                             const float* __restrict__ x,
                                             const float* __restrict__ W1,
                                             int* __restrict__ row_ptr,
                                             int* __restrict__ col,
                                             float* __restrict__ dinv,
                                             unsigned short* __restrict__ pb) {
    __shared__ int hist[BKT_NODES];
    __shared__ int rnk[BKT_NODES];
    __shared__ int wsum[8];
    __shared__ float w1[F_IN * F_HID];
    int b = blockIdx.x, t = threadIdx.x;
    int n = min(cursor[b], CAP);
    int base = bktBase[b];
    if (t < BKT_NODES) hist[t] = 0;
    if (t >= 512 - F_IN * F_HID) w1[t - (512 - F_IN * F_HID)] = W1[t - (512 - F_IN * F_HID)];
    __syncthreads();
    const unsigned* pk = packed + (size_t)b * CAP;
    for (int k = t; k < n; k += 512)
        atomicAdd(&hist[pk[k] & 255], 1);
    __syncthreads();
    int v = (t < BKT_NODES) ? hist[t] : 0;
    int incl = block_incl_scan<8>(v, t, wsum);
    int excl = incl - v;
    if (t < BKT_NODES) rnk[t] = excl;
    __syncthreads();
    for (int k = t; k < n; k += 512) {
        unsigned w = pk[k];
        int r = atomicAdd(&rnk[w & 255], 1);
        col[base + r] = (int)(w >> 8);
    }
    if (t < BKT_NODES) {
        int node = b * BKT_NODES + t;
        if (node < N_NODES) {
            row_ptr[node] = base + excl;
            float di = rsqrtf((float)(1 + v));
            dinv[node] = di;
            if (node == N_NODES - 1) row_ptr[N_NODES] = base + excl + v;
            float xi[F_IN];
#pragma unroll
            for (int k = 0; k < F_IN; k++) xi[k] = x[node * F_IN + k];
            float hv[F_HID];
#pragma unroll
            for (int c = 0; c < F_HID; c++) {
                float h = 0.0f;
#pragma unroll
                for (int k = 0; k < F_IN; k++) h += xi[k] * w1[k * F_HID + c];
                hv[c] = h * di;
            }
            unsigned pkk[8];
#pragma unroll
            for (int q = 0; q < 8; q++)
                pkk[q] = (unsigned)f2bf(hv[2 * q]) | ((unsigned)f2bf(hv[2 * q + 1]) << 16);
            uint4* d4 = (uint4*)(pb + (size_t)node * F_HID);
            d4[0] = make_uint4(pkk[0], pkk[1], pkk[2], pkk[3]);
            d4[1] = make_uint4(pkk[4], pkk[5], pkk[6], pkk[7]);
        }
    }
}

// fused pull + layer-1 epilogue + layer-2 transform:
// S = pull(pb_a); h1 = relu(dinv*S + b1); pb_b = bf16((h1 @ W2) * dinv)
// 4 threads per node (channel quads); h1 exchanged via shfl_xor.
__global__ __launch_bounds__(256) void k_pull_mid(const int* __restrict__ row_ptr,
                                                  const int* __restrict__ col,
                                                  const unsigned short* __restrict__ pb,
                                                  const float* __restrict__ dinv,
                                                  const float* __restrict__ W2,
                                                  const float* __restrict__ b1,
                                                  unsigned short* __restrict__ pb2) {
    __shared__ float w[F_HID * F_HID];
    __shared__ float bb[F_HID];
    int t = threadIdx.x;
    w[t] = W2[t];                        // blockDim == 256 == F_HID*F_HID
    if (t < F_HID) bb[t] = b1[t];
    __syncthreads();
    int gid = blockIdx.x * 256 + t;
    int i = gid >> 2;
    int j = gid & 3;
    if (i >= N_NODES) return;
    int beg = row_ptr[i], end = row_ptr[i + 1];
    float4 acc = row_gather((const ushort4*)pb, i, j, beg, end, col);
    float di = dinv[i];
    float4 mine;
    mine.x = fmaxf(di * acc.x + bb[4 * j + 0], 0.0f);
    mine.y = fmaxf(di * acc.y + bb[4 * j + 1], 0.0f);
    mine.z = fmaxf(di * acc.z + bb[4 * j + 2], 0.0f);
    mine.w = fmaxf(di * acc.w + bb[4 * j + 3], 0.0f);
    float4 o1 = shfl_xor4(mine, 1);
    float4 o2 = shfl_xor4(mine, 2);
    float4 o3 = shfl_xor4(mine, 3);
    // hq_k = h1 channels 4k..4k+3 (value lives on thread j'=k): hq_k = (j==k)?mine:o_{j^k}
    float4 hq0 = (j == 0) ? mine : ((j == 1) ? o1 : ((j == 2) ? o2 : o3));
    float4 hq1 = (j == 1) ? mine : ((j == 0) ? o1 : ((j == 3) ? o2 : o3));
    float4 hq2 = (j == 2) ? mine : ((j == 3) ? o1 : ((j == 0) ? o2 : o3));
    float4 hq3 = (j == 3) ? mine : ((j == 2) ? o1 : ((j == 1) ? o2 : o3));
    float hc[F_HID] = {hq0.x, hq0.y, hq0.z, hq0.w, hq1.x, hq1.y, hq1.z, hq1.w,
                       hq2.x, hq2.y, hq2.z, hq2.w, hq3.x, hq3.y, hq3.z, hq3.w};
    float m0 = 0.0f, m1 = 0.0f, m2 = 0.0f, m3 = 0.0f;
#pragma unroll
    for (int c = 0; c < F_HID; c++) {
        float4 wv = *(const float4*)&w[c * F_HID + 4 * j];
        float hv = hc[c];
        m0 += hv * wv.x; m1 += hv * wv.y; m2 += hv * wv.z; m3 += hv * wv.w;
    }
    unsigned p0 = (unsigned)f2bf(m0 * di) | ((unsigned)f2bf(m1 * di) << 16);
    unsigned p1 = (unsigned)f2bf(m2 * di) | ((unsigned)f2bf(m3 * di) << 16);
    *(uint2*)(pb2 + (size_t)i * F_HID + 4 * j) = make_uint2(p0, p1);
}

// fused pull + layer-2 epilogue + pool:
// S = pull(pb_b); h2 = relu(dinv*S + b2); LDS per-graph accumulate -> out/cnt
__global__ __launch_bounds__(256) void k_pull_pool(const int* __restrict__ row_ptr,
                                                   const int* __restrict__ col,
                                                   const unsigned short* __restrict__ pb,
                                                   const float* __restrict__ dinv,
                                                   const int* __restrict__ batch,
                                                   const float* __restrict__ b2,
                                                   float* __restrict__ out,
                                                   float* __restrict__ cnt) {
    __shared__ float bb[F_HID];
    __shared__ float acc2[8][F_HID];
    __shared__ int gcnt[8];
    __shared__ int g0s;
    int t = threadIdx.x;
    if (t < F_HID) bb[t] = b2[t];
    if (t < 8) gcnt[t] = 0;
    if (t < 8 * F_HID) ((float*)acc2)[t] = 0.0f;
    int blk0node = blockIdx.x * 64;
    if (t == 0) g0s = batch[blk0node < N_NODES ? blk0node : N_NODES - 1];
    __syncthreads();
    int g0 = g0s;
    int gid = blockIdx.x * 256 + t;
    int i = gid >> 2;
    int j = gid & 3;
    if (i < N_NODES) {
        int beg = row_ptr[i], end = row_ptr[i + 1];
        float4 acc = row_gather((const ushort4*)pb, i, j, beg, end, col);
        float di = dinv[i];
        float h0 = fmaxf(di * acc.x + bb[4 * j + 0], 0.0f);
        float h1 = fmaxf(di * acc.y + bb[4 * j + 1], 0.0f);
        float h2 = fmaxf(di * acc.z + bb[4 * j + 2], 0.0f);
        float h3 = fmaxf(di * acc.w + bb[4 * j + 3], 0.0f);
        int g = batch[i];
        int l = g - g0;
        if (l >= 0 && l < 8) {
            atomicAdd(&acc2[l][4 * j + 0], h0);
            atomicAdd(&acc2[l][4 * j + 1], h1);
            atomicAdd(&acc2[l][4 * j + 2], h2);
            atomicAdd(&acc2[l][4 * j + 3], h3);
            if (j == 0) atomicAdd(&gcnt[l], 1);
        } else {
            atomicAdd(&out[g * F_HID + 4 * j + 0], h0);
            atomicAdd(&out[g * F_HID + 4 * j + 1], h1);
            atomicAdd(&out[g * F_HID + 4 * j + 2], h2);
            atomicAdd(&out[g * F_HID + 4 * j + 3], h3);
            if (j == 0) atomicAdd(&cnt[g], 1.0f);
        }
    }
    __syncthreads();
    if (t < 8 * F_HID) {
        int l = t >> 4, c = t & 15;
        if (gcnt[l] > 0) atomicAdd(&out[(g0 + l) * F_HID + c], acc2[l][c]);
    }
    if (t < 8 && gcnt[t] > 0) atomicAdd(&cnt[g0 + t], (float)gcnt[t]);
}

__global__ void k_div(float* __restrict__ out, const float* __restrict__ cnt) {
    int i = blockIdx.x * blockDim.x + threadIdx.x;
    if (i < N_GRAPHS * F_HID) {
        float c = cnt[i / F_HID];
        out[i] /= fmaxf(c, 1.0f);
    }
}

// ---------------- launcher ----------------

extern "C" void kernel_launch(void* const* d_in, const int* in_sizes, int n_in,
                              void* d_out, int out_size, void* d_ws, size_t ws_size,
                              hipStream_t stream) {
    const float* x     = (const float*)d_in[0];
    const int*   ei    = (const int*)d_in[1];   // [2, N_EDGES]
    const int*   batch = (const int*)d_in[2];
    const float* W1    = (const float*)d_in[3];
    const float* b1    = (const float*)d_in[4];
    const float* W2    = (const float*)d_in[5];
    const float* b2    = (const float*)d_in[6];
    float* out = (float*)d_out;

    int*            cursor  = (int*)d_ws;                                  // 512
    int*            bktBase = cursor + 512;                                // 512
    unsigned*       packed  = (unsigned*)(bktBase + 512);                  // NBKT*CAP
    int*            row_ptr = (int*)(packed + (size_t)NBKT * CAP);         // 100352
    int*            col     = row_ptr + 100352;                            // N_EDGES
    float*          dinv    = (float*)(col + N_EDGES);                     // N
    unsigned short* pb_a    = (unsigned short*)(dinv + N_NODES);           // 16N ushort
    unsigned short* pb_b    = pb_a + (size_t)N_NODES * F_HID;              // 16N ushort
    float*          cnt     = (float*)(pb_b + (size_t)N_NODES * F_HID);    // 512

    const int* src = ei;
    const int* dst = ei + N_EDGES;

    const int nb_pull = (N_NODES * 4 + 255) / 256;

    k_zero<<<(N_GRAPHS * F_HID + 255) / 256, 256, 0, stream>>>(cursor, out, cnt);
    k_part<<<NCHUNK, PBLK, 0, stream>>>(src, dst, cursor, packed);
    k_scanb<<<1, 512, 0, stream>>>(cursor, bktBase);
    k_csr<<<NBKT, 512, 0, stream>>>(cursor, bktBase, packed, x, W1,
                                    row_ptr, col, dinv, pb_a);
    k_pull_mid<<<nb_pull, 256, 0, stream>>>(row_ptr, col, pb_a, dinv, W2, b1, pb_b);
    k_pull_pool<<<nb_pull, 256, 0, stream>>>(row_ptr, col, pb_b, dinv, batch, b2,
                                             out, cnt);
    k_div<<<(N_GRAPHS * F_HID + 255) / 256, 256, 0, stream>>>(out, cnt);
}

// Round 9
// 200.431 us; speedup vs baseline: 1.1469x; 1.0068x over previous
//
#include <hip/hip_runtime.h>

#define N_NODES  100000
#define N_EDGES  3200000
#define N_GRAPHS 512
#define F_IN     5
#define F_HID    16

#define PBLK   512                      // k_part block size
#define CHUNK  8192                     // edges per k_part workgroup
#define NCHUNK ((N_EDGES + CHUNK - 1) / CHUNK)          // 391
#define BKT_NODES 256                   // nodes per coarse bucket
#define NBKT ((N_NODES + BKT_NODES - 1) / BKT_NODES)    // 391
#define CAP 10240                       // raw mean 8184 (+22 sigma); padded mean 9088 (+11 sigma)

// ---------------- helpers ----------------

__device__ inline unsigned short f2bf(float f) {
    unsigned u = __float_as_uint(f);
    return (unsigned short)((u + 0x7fffu + ((u >> 16) & 1u)) >> 16);   // RNE
}
__device__ inline float bf2f(unsigned short h) {
    return __uint_as_float(((unsigned)h) << 16);
}
__device__ inline float4 cvt4(ushort4 u) {
    return make_float4(bf2f(u.x), bf2f(u.y), bf2f(u.z), bf2f(u.w));
}
__device__ inline float4 shfl_xor4(float4 v, int m) {
    return make_float4(__shfl_xor(v.x, m, 64), __shfl_xor(v.y, m, 64),
                       __shfl_xor(v.z, m, 64), __shfl_xor(v.w, m, 64));
}

// block-wide inclusive scan via wave shfl; NW = number of waves (<=8)
template <int NW>
__device__ inline int block_incl_scan(int v, int t, int* wsum) {
    int lane = t & 63, wave = t >> 6;
    int x = v;
#pragma unroll
    for (int o = 1; o < 64; o <<= 1) {
        int y = __shfl_up(x, o, 64);
        if (lane >= o) x += y;
    }
    if (lane == 63) wsum[wave] = x;
    __syncthreads();
    if (t < 64) {
        int w = (t < NW) ? wsum[t] : 0;
#pragma unroll
        for (int o = 1; o < NW; o <<= 1) {
            int y = __shfl_up(w, o, 64);
            if (t >= o) w += y;
        }
        if (t < NW) wsum[t] = w;
    }
    __syncthreads();
    return x + (wave ? wsum[wave - 1] : 0);
}

// gather-accumulate over one padded row (len % 8 == 0, beg 4-aligned);
// channels 4j..4j+3. Dummy entries point at zeroed row N_NODES.
__device__ inline float4 row_gather8(const ushort4* __restrict__ pb4, int i, int j,
                                     int beg, int len, const int* __restrict__ col) {
    float4 acc = cvt4(pb4[i * 4 + j]);                // self loop
    for (int k = 0; k < len; k += 8) {
        int4 c0 = *(const int4*)(col + beg + k);
        int4 c1 = *(const int4*)(col + beg + k + 4);
        ushort4 a0 = pb4[c0.x * 4 + j], a1 = pb4[c0.y * 4 + j];
        ushort4 a2 = pb4[c0.z * 4 + j], a3 = pb4[c0.w * 4 + j];
        ushort4 a4 = pb4[c1.x * 4 + j], a5 = pb4[c1.y * 4 + j];
        ushort4 a6 = pb4[c1.z * 4 + j], a7 = pb4[c1.w * 4 + j];
        float4 f0 = cvt4(a0), f1 = cvt4(a1), f2 = cvt4(a2), f3 = cvt4(a3);
        float4 f4 = cvt4(a4), f5 = cvt4(a5), f6 = cvt4(a6), f7 = cvt4(a7);
        acc.x += ((f0.x + f1.x) + (f2.x + f3.x)) + ((f4.x + f5.x) + (f6.x + f7.x));
        acc.y += ((f0.y + f1.y) + (f2.y + f3.y)) + ((f4.y + f5.y) + (f6.y + f7.y));
        acc.z += ((f0.z + f1.z) + (f2.z + f3.z)) + ((f4.z + f5.z) + (f6.z + f7.z));
        acc.w += ((f0.w + f1.w) + (f2.w + f3.w)) + ((f4.w + f5.w) + (f6.w + f7.w));
    }
    return acc;
}

// ---------------- kernels ----------------

__global__ void k_zero(int* __restrict__ cursor, float* __restrict__ out,
                       float* __restrict__ cnt, unsigned short* __restrict__ pb_a,
                       unsigned short* __restrict__ pb_b) {
    int i = blockIdx.x * blockDim.x + threadIdx.x;
    if (i < NBKT) cursor[i] = 0;
    if (i < N_GRAPHS * F_HID) out[i] = 0.0f;
    if (i < N_GRAPHS) cnt[i] = 0.0f;
    if (i < F_HID) {                       // zero the dummy rows
        pb_a[(size_t)N_NODES * F_HID + i] = 0;
        pb_b[(size_t)N_NODES * F_HID + i] = 0;
    }
}

// staged counting-sort partition into 391 coarse buckets of dst>>8.
__global__ __launch_bounds__(PBLK) void k_part(const int* __restrict__ src,
                                               const int* __restrict__ dst,
                                               int* __restrict__ cursor,
                                               unsigned* __restrict__ packed) {
    __shared__ int hist[PBLK];
    __shared__ int scn[PBLK];
    __shared__ int rnk[PBLK];
    __shared__ int gbase[PBLK];
    __shared__ int wsum[8];
    int t = threadIdx.x;
    int chunk0 = blockIdx.x * CHUNK;
    int n = min(CHUNK, N_EDGES - chunk0);
    hist[t] = 0;
    __syncthreads();
    int ls[CHUNK / PBLK], ld[CHUNK / PBLK];
    for (int k = t, idx = 0; k < n; k += PBLK, idx++) {
        ls[idx] = src[chunk0 + k];
        ld[idx] = dst[chunk0 + k];
        atomicAdd(&hist[ld[idx] >> 8], 1);
    }
    __syncthreads();
    int v = hist[t];
    int incl = block_incl_scan<8>(v, t, wsum);
    int excl = incl - v;
    scn[t] = excl;
    rnk[t] = excl;
    gbase[t] = (v > 0) ? atomicAdd(&cursor[t], v) : 0;
    __syncthreads();
    for (int k = t, idx = 0; k < n; k += PBLK, idx++) {
        int d = ld[idx], s = ls[idx];
        int b = d >> 8;
        int r = atomicAdd(&rnk[b], 1);
        int g = gbase[b] + (r - scn[b]);
        if (g < CAP)
            packed[(size_t)b * CAP + g] = ((unsigned)s << 8) | (unsigned)(d & 255);
    }
}

// per coarse bucket: node-level counting sort into BUCKET-LOCAL col
// (rows padded to multiple of 8 with dummy node N_NODES); emits per-node
// (beg,len), dinv, and fused layer-1 transform pb = bf16((x @ W1) * dinv)
__global__ __launch_bounds__(512) void k_csr(const int* __restrict__ cursor,
                                             const unsigned* __restrict__ packed,
                                             const float* __restrict__ x,
                                             const float* __restrict__ W1,
                                             int2* __restrict__ rowbc,
                                             int* __restrict__ col,
                                             float* __restrict__ dinv,
                                             unsigned short* __restrict__ pb) {
    __shared__ int hist[BKT_NODES];
    __shared__ int rnk[BKT_NODES];
    __shared__ int wsum[8];
    __shared__ float w1[F_IN * F_HID];
    int b = blockIdx.x, t = threadIdx.x;
    int n = min(cursor[b], CAP);
    int base = b * CAP;
    if (t < BKT_NODES) hist[t] = 0;
    if (t >= 512 - F_IN * F_HID) w1[t - (512 - F_IN * F_HID)] = W1[t - (512 - F_IN * F_HID)];
    __syncthreads();
    const unsigned* pk = packed + (size_t)b * CAP;
    for (int k = t; k < n; k += 512)
        atomicAdd(&hist[pk[k] & 255], 1);
    __syncthreads();
    int v = (t < BKT_NODES) ? hist[t] : 0;
    int len = (v + 7) & ~7;                       // padded row length
    int incl = block_incl_scan<8>(len, t, wsum);
    int excl = incl - len;
    if (t < BKT_NODES) rnk[t] = excl;
    __syncthreads();
    for (int k = t; k < n; k += 512) {
        unsigned w = pk[k];
        int r = atomicAdd(&rnk[w & 255], 1);
        if (r < CAP) col[base + r] = (int)(w >> 8);
    }
    if (t < BKT_NODES) {
        int node = b * BKT_NODES + t;
        if (node < N_NODES) {
            int mylen = min(len, ((CAP - min(excl, CAP)) & ~7));
            // pad [v, mylen) with dummy node
            for (int q = v; q < mylen; q++) {
                int r = excl + q;
                if (r < CAP) col[base + r] = N_NODES;
            }
            rowbc[node] = make_int2(base + excl, mylen);
            float di = rsqrtf((float)(1 + v));
            dinv[node] = di;
            float xi[F_IN];
#pragma unroll
            for (int k = 0; k < F_IN; k++) xi[k] = x[node * F_IN + k];
            float hv[F_HID];
#pragma unroll
            for (int c = 0; c < F_HID; c++) {
                float h = 0.0f;
#pragma unroll
                for (int k = 0; k < F_IN; k++) h += xi[k] * w1[k * F_HID + c];
                hv[c] = h * di;
            }
            unsigned pkk[8];
#pragma unroll
            for (int q = 0; q < 8; q++)
                pkk[q] = (unsigned)f2bf(hv[2 * q]) | ((unsigned)f2bf(hv[2 * q + 1]) << 16);
            uint4* d4 = (uint4*)(pb + (size_t)node * F_HID);
            d4[0] = make_uint4(pkk[0], pkk[1], pkk[2], pkk[3]);
            d4[1] = make_uint4(pkk[4], pkk[5], pkk[6], pkk[7]);
        }
    }
}

// fused pull + layer-1 epilogue + layer-2 transform
__global__ __launch_bounds__(256) void k_pull_mid(const int2* __restrict__ rowbc,
                                                  const int* __restrict__ col,
                                                  const unsigned short* __restrict__ pb,
                                                  const float* __restrict__ dinv,
                                                  const float* __restrict__ W2,
                                                  const float* __restrict__ b1,
                                                  unsigned short* __restrict__ pb2) {
    __shared__ float w[F_HID * F_HID];
    __shared__ float bb[F_HID];
    int t = threadIdx.x;
    w[t] = W2[t];                        // blockDim == 256 == F_HID*F_HID
    if (t < F_HID) bb[t] = b1[t];
    __syncthreads();
    int gid = blockIdx.x * 256 + t;
    int i = gid >> 2;
    int j = gid & 3;
    if (i >= N_NODES) return;
    int2 rc = rowbc[i];
    float4 acc = row_gather8((const ushort4*)pb, i, j, rc.x, rc.y, col);
    float di = dinv[i];
    float4 mine;
    mine.x = fmaxf(di * acc.x + bb[4 * j + 0], 0.0f);
    mine.y = fmaxf(di * acc.y + bb[4 * j + 1], 0.0f);
    mine.z = fmaxf(di * acc.z + bb[4 * j + 2], 0.0f);
    mine.w = fmaxf(di * acc.w + bb[4 * j + 3], 0.0f);
    float4 o1 = shfl_xor4(mine, 1);
    float4 o2 = shfl_xor4(mine, 2);
    float4 o3 = shfl_xor4(mine, 3);
    float4 hq0 = (j == 0) ? mine : ((j == 1) ? o1 : ((j == 2) ? o2 : o3));
    float4 hq1 = (j == 1) ? mine : ((j == 0) ? o1 : ((j == 3) ? o2 : o3));
    float4 hq2 = (j == 2) ? mine : ((j == 3) ? o1 : ((j == 0) ? o2 : o3));
    float4 hq3 = (j == 3) ? mine : ((j == 2) ? o1 : ((j == 1) ? o2 : o3));
    float hc[F_HID] = {hq0.x, hq0.y, hq0.z, hq0.w, hq1.x, hq1.y, hq1.z, hq1.w,
                       hq2.x, hq2.y, hq2.z, hq2.w, hq3.x, hq3.y, hq3.z, hq3.w};
    float m0 = 0.0f, m1 = 0.0f, m2 = 0.0f, m3 = 0.0f;
#pragma unroll
    for (int c = 0; c < F_HID; c++) {
        float4 wv = *(const float4*)&w[c * F_HID + 4 * j];
        float hv = hc[c];
        m0 += hv * wv.x; m1 += hv * wv.y; m2 += hv * wv.z; m3 += hv * wv.w;
    }
    unsigned p0 = (unsigned)f2bf(m0 * di) | ((unsigned)f2bf(m1 * di) << 16);
    unsigned p1 = (unsigned)f2bf(m2 * di) | ((unsigned)f2bf(m3 * di) << 16);
    *(uint2*)(pb2 + (size_t)i * F_HID + 4 * j) = make_uint2(p0, p1);
}

// fused pull + layer-2 epilogue + pool
__global__ __launch_bounds__(256) void k_pull_pool(const int2* __restrict__ rowbc,
                                                   const int* __restrict__ col,
                                                   const unsigned short* __restrict__ pb,
                                                   const float* __restrict__ dinv,
                                                   const int* __restrict__ batch,
                                                   const float* __restrict__ b2,
                                                   float* __restrict__ out,
                                                   float* __restrict__ cnt) {
    __shared__ float bb[F_HID];
    __shared__ float acc2[8][F_HID];
    __shared__ int gcnt[8];
    __shared__ int g0s;
    int t = threadIdx.x;
    if (t < F_HID) bb[t] = b2[t];
    if (t < 8) gcnt[t] = 0;
    if (t < 8 * F_HID) ((float*)acc2)[t] = 0.0f;
    int blk0node = blockIdx.x * 64;
    if (t == 0) g0s = batch[blk0node < N_NODES ? blk0node : N_NODES - 1];
    __syncthreads();
    int g0 = g0s;
    int gid = blockIdx.x * 256 + t;
    int i = gid >> 2;
    int j = gid & 3;
    if (i < N_NODES) {
        int2 rc = rowbc[i];
        float4 acc = row_gather8((const ushort4*)pb, i, j, rc.x, rc.y, col);
        float di = dinv[i];
        float h0 = fmaxf(di * acc.x + bb[4 * j + 0], 0.0f);
        float h1 = fmaxf(di * acc.y + bb[4 * j + 1], 0.0f);
        float h2 = fmaxf(di * acc.z + bb[4 * j + 2], 0.0f);
        float h3 = fmaxf(di * acc.w + bb[4 * j + 3], 0.0f);
        int g = batch[i];
        int l = g - g0;
        if (l >= 0 && l < 8) {
            atomicAdd(&acc2[l][4 * j + 0], h0);
            atomicAdd(&acc2[l][4 * j + 1], h1);
            atomicAdd(&acc2[l][4 * j + 2], h2);
            atomicAdd(&acc2[l][4 * j + 3], h3);
            if (j == 0) atomicAdd(&gcnt[l], 1);
        } else {
            atomicAdd(&out[g * F_HID + 4 * j + 0], h0);
            atomicAdd(&out[g * F_HID + 4 * j + 1], h1);
            atomicAdd(&out[g * F_HID + 4 * j + 2], h2);
            atomicAdd(&out[g * F_HID + 4 * j + 3], h3);
            if (j == 0) atomicAdd(&cnt[g], 1.0f);
        }
    }
    __syncthreads();
    if (t < 8 * F_HID) {
        int l = t >> 4, c = t & 15;
        if (gcnt[l] > 0) atomicAdd(&out[(g0 + l) * F_HID + c], acc2[l][c]);
    }
    if (t < 8 && gcnt[t] > 0) atomicAdd(&cnt[g0 + t], (float)gcnt[t]);
}

__global__ void k_div(float* __restrict__ out, const float* __restrict__ cnt) {
    int i = blockIdx.x * blockDim.x + threadIdx.x;
    if (i < N_GRAPHS * F_HID) {
        float c = cnt[i / F_HID];
        out[i] /= fmaxf(c, 1.0f);
    }
}

// ---------------- launcher ----------------

extern "C" void kernel_launch(void* const* d_in, const int* in_sizes, int n_in,
                              void* d_out, int out_size, void* d_ws, size_t ws_size,
                              hipStream_t stream) {
    const float* x     = (const float*)d_in[0];
    const int*   ei    = (const int*)d_in[1];   // [2, N_EDGES]
    const int*   batch = (const int*)d_in[2];
    const float* W1    = (const float*)d_in[3];
    const float* b1    = (const float*)d_in[4];
    const float* W2    = (const float*)d_in[5];
    const float* b2    = (const float*)d_in[6];
    float* out = (float*)d_out;

    int*            cursor = (int*)d_ws;                                   // 512
    unsigned*       packed = (unsigned*)(cursor + 512);                    // NBKT*CAP
    int2*           rowbc  = (int2*)(packed + (size_t)NBKT * CAP);         // N int2
    int*            col    = (int*)(rowbc + N_NODES);                      // NBKT*CAP
    float*          dinv   = (float*)(col + (size_t)NBKT * CAP);           // N
    unsigned short* pb_a   = (unsigned short*)(dinv + N_NODES);            // (N+1)*16
    unsigned short* pb_b   = pb_a + (size_t)(N_NODES + 1) * F_HID;         // (N+1)*16
    float*          cnt    = (float*)(pb_b + (size_t)(N_NODES + 1) * F_HID); // 512

    const int* src = ei;
    const int* dst = ei + N_EDGES;

    const int nb_pull = (N_NODES * 4 + 255) / 256;

    k_zero<<<(N_GRAPHS * F_HID + 255) / 256, 256, 0, stream>>>(cursor, out, cnt,
                                                               pb_a, pb_b);
    k_part<<<NCHUNK, PBLK, 0, stream>>>(src, dst, cursor, packed);
    k_csr<<<NBKT, 512, 0, stream>>>(cursor, packed, x, W1, rowbc, col, dinv, pb_a);
    k_pull_mid<<<nb_pull, 256, 0, stream>>>(rowbc, col, pb_a, dinv, W2, b1, pb_b);
    k_pull_pool<<<nb_pull, 256, 0, stream>>>(rowbc, col, pb_b, dinv, batch, b2,
                                             out, cnt);
    k_div<<<(N_GRAPHS * F_HID + 255) / 256, 256, 0, stream>>>(out, cnt);
}

// Round 10
// 189.806 us; speedup vs baseline: 1.2112x; 1.0560x over previous
//
#include <hip/hip_runtime.h>

#define N_NODES  100000
#define N_EDGES  3200000
#define N_GRAPHS 512
#define F_IN     5
#define F_HID    16

#define PBLK   512                      // k_part block size
#define CHUNK  8192                     // edges per k_part workgroup
#define NCHUNK ((N_EDGES + CHUNK - 1) / CHUNK)          // 391
#define BKT_NODES 256                   // nodes per coarse bucket
#define NBKT ((N_NODES + BKT_NODES - 1) / BKT_NODES)    // 391
#define SHARDS 8                        // cursor shards per bucket
#define CAP_S  1280                     // per-(bucket,shard) capacity: mean 1027, +7.9 sigma
#define CAP    (SHARDS * CAP_S)         // 10240 per bucket

// ---------------- helpers ----------------

__device__ inline unsigned short f2bf(float f) {
    unsigned u = __float_as_uint(f);
    return (unsigned short)((u + 0x7fffu + ((u >> 16) & 1u)) >> 16);   // RNE
}
__device__ inline float bf2f(unsigned short h) {
    return __uint_as_float(((unsigned)h) << 16);
}
__device__ inline float4 cvt4(ushort4 u) {
    return make_float4(bf2f(u.x), bf2f(u.y), bf2f(u.z), bf2f(u.w));
}
__device__ inline float4 shfl_xor4(float4 v, int m) {
    return make_float4(__shfl_xor(v.x, m, 64), __shfl_xor(v.y, m, 64),
                       __shfl_xor(v.z, m, 64), __shfl_xor(v.w, m, 64));
}

// block-wide inclusive scan via wave shfl; NW = number of waves (<=8)
template <int NW>
__device__ inline int block_incl_scan(int v, int t, int* wsum) {
    int lane = t & 63, wave = t >> 6;
    int x = v;
#pragma unroll
    for (int o = 1; o < 64; o <<= 1) {
        int y = __shfl_up(x, o, 64);
        if (lane >= o) x += y;
    }
    if (lane == 63) wsum[wave] = x;
    __syncthreads();
    if (t < 64) {
        int w = (t < NW) ? wsum[t] : 0;
#pragma unroll
        for (int o = 1; o < NW; o <<= 1) {
            int y = __shfl_up(w, o, 64);
            if (t >= o) w += y;
        }
        if (t < NW) wsum[t] = w;
    }
    __syncthreads();
    return x + (wave ? wsum[wave - 1] : 0);
}

// half-row gather (len % 8 == 0): half h takes 8-blocks h, h+2, h+4, ...
// channels 4j..4j+3. Dummy entries point at zeroed row N_NODES.
__device__ inline float4 row_gather8s(const ushort4* __restrict__ pb4, int i, int j,
                                      int half, int beg, int len,
                                      const int* __restrict__ col) {
    float4 acc = half ? make_float4(0.f, 0.f, 0.f, 0.f)
                      : cvt4(pb4[i * 4 + j]);          // self loop once
    for (int k = half * 8; k < len; k += 16) {
        int4 c0 = *(const int4*)(col + beg + k);
        int4 c1 = *(const int4*)(col + beg + k + 4);
        ushort4 a0 = pb4[c0.x * 4 + j], a1 = pb4[c0.y * 4 + j];
        ushort4 a2 = pb4[c0.z * 4 + j], a3 = pb4[c0.w * 4 + j];
        ushort4 a4 = pb4[c1.x * 4 + j], a5 = pb4[c1.y * 4 + j];
        ushort4 a6 = pb4[c1.z * 4 + j], a7 = pb4[c1.w * 4 + j];
        float4 f0 = cvt4(a0), f1 = cvt4(a1), f2 = cvt4(a2), f3 = cvt4(a3);
        float4 f4 = cvt4(a4), f5 = cvt4(a5), f6 = cvt4(a6), f7 = cvt4(a7);
        acc.x += ((f0.x + f1.x) + (f2.x + f3.x)) + ((f4.x + f5.x) + (f6.x + f7.x));
        acc.y += ((f0.y + f1.y) + (f2.y + f3.y)) + ((f4.y + f5.y) + (f6.y + f7.y));
        acc.z += ((f0.z + f1.z) + (f2.z + f3.z)) + ((f4.z + f5.z) + (f6.z + f7.z));
        acc.w += ((f0.w + f1.w) + (f2.w + f3.w)) + ((f4.w + f5.w) + (f6.w + f7.w));
    }
    return acc;
}

// ---------------- kernels ----------------

__global__ void k_zero(int* __restrict__ cursor, float* __restrict__ out,
                       float* __restrict__ cnt, unsigned short* __restrict__ pb_a,
                       unsigned short* __restrict__ pb_b) {
    int i = blockIdx.x * blockDim.x + threadIdx.x;
    if (i < NBKT * SHARDS) cursor[i] = 0;
    if (i < N_GRAPHS * F_HID) out[i] = 0.0f;
    if (i < N_GRAPHS) cnt[i] = 0.0f;
    if (i < F_HID) {                       // zero the dummy rows
        pb_a[(size_t)N_NODES * F_HID + i] = 0;
        pb_b[(size_t)N_NODES * F_HID + i] = 0;
    }
}

// staged counting-sort partition into 391 coarse buckets of dst>>8,
// with 8-way sharded reservation cursors (chain 391 -> 49 RMWs/counter).
// Also counts nodes-per-graph from sorted batch (block b covers nodes
// [b*256, b*256+256)) for the fused pool normalization.
__global__ __launch_bounds__(PBLK) void k_part(const int* __restrict__ src,
                                               const int* __restrict__ dst,
                                               const int* __restrict__ batch,
                                               int* __restrict__ cursor,
                                               unsigned* __restrict__ packed,
                                               float* __restrict__ cnt) {
    __shared__ int hist[PBLK];
    __shared__ int scn[PBLK];
    __shared__ int rnk[PBLK];
    __shared__ int gbase[PBLK];
    __shared__ int wsum[8];
    __shared__ int bcnt[8];
    __shared__ int g0s;
    int t = threadIdx.x;
    int blk = blockIdx.x;
    int s = blk & (SHARDS - 1);
    int chunk0 = blk * CHUNK;
    int n = min(CHUNK, N_EDGES - chunk0);
    hist[t] = 0;
    if (t < 8) bcnt[t] = 0;
    if (t == 0) {
        int nb = blk * BKT_NODES;
        g0s = batch[nb < N_NODES ? nb : N_NODES - 1];
    }
    __syncthreads();
    int ls[CHUNK / PBLK], ld[CHUNK / PBLK];
    for (int k = t, idx = 0; k < n; k += PBLK, idx++) {
        ls[idx] = src[chunk0 + k];
        ld[idx] = dst[chunk0 + k];
        atomicAdd(&hist[ld[idx] >> 8], 1);
    }
    // graph-size counting for this block's node slice
    if (t < BKT_NODES) {
        int i2 = blk * BKT_NODES + t;
        if (i2 < N_NODES) {
            int g = batch[i2];
            int l = g - g0s;
            if (l >= 0 && l < 8) atomicAdd(&bcnt[l], 1);
            else atomicAdd(&cnt[g], 1.0f);
        }
    }
    __syncthreads();
    int v = hist[t];
    int incl = block_incl_scan<8>(v, t, wsum);
    int excl = incl - v;
    scn[t] = excl;
    rnk[t] = excl;
    gbase[t] = (v > 0) ? atomicAdd(&cursor[t * SHARDS + s], v) : 0;
    if (t < 8 && bcnt[t] > 0) atomicAdd(&cnt[g0s + t], (float)bcnt[t]);
    __syncthreads();
    for (int k = t, idx = 0; k < n; k += PBLK, idx++) {
        int d = ld[idx], sr = ls[idx];
        int b = d >> 8;
        int r = atomicAdd(&rnk[b], 1);
        int g = gbase[b] + (r - scn[b]);
        if (g < CAP_S)
            packed[(size_t)b * CAP + s * CAP_S + g] =
                ((unsigned)sr << 8) | (unsigned)(d & 255);
    }
}

// per coarse bucket: node-level counting sort (over 8 shard segments) into
// BUCKET-LOCAL col (rows padded to multiple of 8 with dummy node N_NODES);
// emits per-node (beg,len), dinv, and fused layer-1 transform
// pb = bf16((x @ W1) * dinv)
__global__ __launch_bounds__(512) void k_csr(const int* __restrict__ cursor,
                                             const unsigned* __restrict__ packed,
                                             const float* __restrict__ x,
                                             const float* __restrict__ W1,
                                             int2* __restrict__ rowbc,
                                             int* __restrict__ col,
                                             float* __restrict__ dinv,
                                             unsigned short* __restrict__ pb) {
    __shared__ int hist[BKT_NODES];
    __shared__ int rnk[BKT_NODES];
    __shared__ int wsum[8];
    __shared__ int ns[SHARDS];
    __shared__ float w1[F_IN * F_HID];
    int b = blockIdx.x, t = threadIdx.x;
    int base = b * CAP;
    if (t < BKT_NODES) hist[t] = 0;
    if (t < SHARDS) ns[t] = min(cursor[b * SHARDS + t], CAP_S);
    if (t >= 512 - F_IN * F_HID) w1[t - (512 - F_IN * F_HID)] = W1[t - (512 - F_IN * F_HID)];
    __syncthreads();
    const unsigned* pk = packed + (size_t)b * CAP;
#pragma unroll
    for (int s = 0; s < SHARDS; s++) {
        int m = ns[s];
        const unsigned* pks = pk + s * CAP_S;
        for (int k = t; k < m; k += 512)
            atomicAdd(&hist[pks[k] & 255], 1);
    }
    __syncthreads();
    int v = (t < BKT_NODES) ? hist[t] : 0;
    int len = (v + 7) & ~7;                       // padded row length
    int incl = block_incl_scan<8>(len, t, wsum);
    int excl = incl - len;
    if (t < BKT_NODES) rnk[t] = excl;
    __syncthreads();
#pragma unroll
    for (int s = 0; s < SHARDS; s++) {
        int m = ns[s];
        const unsigned* pks = pk + s * CAP_S;
        for (int k = t; k < m; k += 512) {
            unsigned w = pks[k];
            int r = atomicAdd(&rnk[w & 255], 1);
            if (r < CAP) col[base + r] = (int)(w >> 8);
        }
    }
    if (t < BKT_NODES) {
        int node = b * BKT_NODES + t;
        if (node < N_NODES) {
            int mylen = min(len, ((CAP - min(excl, CAP)) & ~7));
            for (int q = v; q < mylen; q++) {     // pad with dummy node
                int r = excl + q;
                if (r < CAP) col[base + r] = N_NODES;
            }
            rowbc[node] = make_int2(base + excl, mylen);
            float di = rsqrtf((float)(1 + v));
            dinv[node] = di;
            float xi[F_IN];
#pragma unroll
            for (int k = 0; k < F_IN; k++) xi[k] = x[node * F_IN + k];
            float hv[F_HID];
#pragma unroll
            for (int c = 0; c < F_HID; c++) {
                float h = 0.0f;
#pragma unroll
                for (int k = 0; k < F_IN; k++) h += xi[k] * w1[k * F_HID + c];
                hv[c] = h * di;
            }
            unsigned pkk[8];
#pragma unroll
            for (int q = 0; q < 8; q++)
                pkk[q] = (unsigned)f2bf(hv[2 * q]) | ((unsigned)f2bf(hv[2 * q + 1]) << 16);
            uint4* d4 = (uint4*)(pb + (size_t)node * F_HID);
            d4[0] = make_uint4(pkk[0], pkk[1], pkk[2], pkk[3]);
            d4[1] = make_uint4(pkk[4], pkk[5], pkk[6], pkk[7]);
        }
    }
}

// fused pull + layer-1 epilogue + layer-2 transform; 8 threads/node
// (two halves of the row, combined via shfl_xor 4)
__global__ __launch_bounds__(256) void k_pull_mid(const int2* __restrict__ rowbc,
                                                  const int* __restrict__ col,
                                                  const unsigned short* __restrict__ pb,
                                                  const float* __restrict__ dinv,
                                                  const float* __restrict__ W2,
                                                  const float* __restrict__ b1,
                                                  unsigned short* __restrict__ pb2) {
    __shared__ float w[F_HID * F_HID];
    __shared__ float bb[F_HID];
    int t = threadIdx.x;
    w[t] = W2[t];                        // blockDim == 256 == F_HID*F_HID
    if (t < F_HID) bb[t] = b1[t];
    __syncthreads();
    int gid = blockIdx.x * 256 + t;      // grid = N_NODES*8/256 exactly
    int i = gid >> 3;
    int half = (gid >> 2) & 1;
    int j = gid & 3;
    int2 rc = rowbc[i];
    float4 acc = row_gather8s((const ushort4*)pb, i, j, half, rc.x, rc.y, col);
    acc.x += __shfl_xor(acc.x, 4, 64);
    acc.y += __shfl_xor(acc.y, 4, 64);
    acc.z += __shfl_xor(acc.z, 4, 64);
    acc.w += __shfl_xor(acc.w, 4, 64);
    float di = dinv[i];
    float4 mine;
    mine.x = fmaxf(di * acc.x + bb[4 * j + 0], 0.0f);
    mine.y = fmaxf(di * acc.y + bb[4 * j + 1], 0.0f);
    mine.z = fmaxf(di * acc.z + bb[4 * j + 2], 0.0f);
    mine.w = fmaxf(di * acc.w + bb[4 * j + 3], 0.0f);
    float4 o1 = shfl_xor4(mine, 1);
    float4 o2 = shfl_xor4(mine, 2);
    float4 o3 = shfl_xor4(mine, 3);
    float4 hq0 = (j == 0) ? mine : ((j == 1) ? o1 : ((j == 2) ? o2 : o3));
    float4 hq1 = (j == 1) ? mine : ((j == 0) ? o1 : ((j == 3) ? o2 : o3));
    float4 hq2 = (j == 2) ? mine : ((j == 3) ? o1 : ((j == 0) ? o2 : o3));
    float4 hq3 = (j == 3) ? mine : ((j == 2) ? o1 : ((j == 1) ? o2 : o3));
    float hc[F_HID] = {hq0.x, hq0.y, hq0.z, hq0.w, hq1.x, hq1.y, hq1.z, hq1.w,
                       hq2.x, hq2.y, hq2.z, hq2.w, hq3.x, hq3.y, hq3.z, hq3.w};
    float m0 = 0.0f, m1 = 0.0f, m2 = 0.0f, m3 = 0.0f;
#pragma unroll
    for (int c = 0; c < F_HID; c++) {
        float4 wv = *(const float4*)&w[c * F_HID + 4 * j];
        float hv = hc[c];
        m0 += hv * wv.x; m1 += hv * wv.y; m2 += hv * wv.z; m3 += hv * wv.w;
    }
    if (half == 0) {
        unsigned p0 = (unsigned)f2bf(m0 * di) | ((unsigned)f2bf(m1 * di) << 16);
        unsigned p1 = (unsigned)f2bf(m2 * di) | ((unsigned)f2bf(m3 * di) << 16);
        *(uint2*)(pb2 + (size_t)i * F_HID + 4 * j) = make_uint2(p0, p1);
    }
}

// fused pull + layer-2 epilogue + mean-pool (division folded in via cnt
// computed by k_part); 8 threads/node
__global__ __launch_bounds__(256) void k_pull_pool(const int2* __restrict__ rowbc,
                                                   const int* __restrict__ col,
                                                   const unsigned short* __restrict__ pb,
                                                   const float* __restrict__ dinv,
                                                   const int* __restrict__ batch,
                                                   const float* __restrict__ b2,
                                                   const float* __restrict__ cnt,
                                                   float* __restrict__ out) {
    __shared__ float bb[F_HID];
    __shared__ float acc2[8][F_HID];
    __shared__ int gcnt[8];
    __shared__ int g0s;
    int t = threadIdx.x;
    if (t < F_HID) bb[t] = b2[t];
    if (t < 8) gcnt[t] = 0;
    if (t < 8 * F_HID) ((float*)acc2)[t] = 0.0f;
    int blk0node = blockIdx.x * 32;                 // 32 nodes per block
    if (t == 0) g0s = batch[blk0node < N_NODES ? blk0node : N_NODES - 1];
    __syncthreads();
    int g0 = g0s;
    int gid = blockIdx.x * 256 + t;
    int i = gid >> 3;
    int half = (gid >> 2) & 1;
    int j = gid & 3;
    int2 rc = rowbc[i];
    float4 acc = row_gather8s((const ushort4*)pb, i, j, half, rc.x, rc.y, col);
    acc.x += __shfl_xor(acc.x, 4, 64);
    acc.y += __shfl_xor(acc.y, 4, 64);
    acc.z += __shfl_xor(acc.z, 4, 64);
    acc.w += __shfl_xor(acc.w, 4, 64);
    if (half == 0) {
        float di = dinv[i];
        float h0 = fmaxf(di * acc.x + bb[4 * j + 0], 0.0f);
        float h1 = fmaxf(di * acc.y + bb[4 * j + 1], 0.0f);
        float h2 = fmaxf(di * acc.z + bb[4 * j + 2], 0.0f);
        float h3 = fmaxf(di * acc.w + bb[4 * j + 3], 0.0f);
        int g = batch[i];
        int l = g - g0;
        if (l >= 0 && l < 8) {
            atomicAdd(&acc2[l][4 * j + 0], h0);
            atomicAdd(&acc2[l][4 * j + 1], h1);
            atomicAdd(&acc2[l][4 * j + 2], h2);
            atomicAdd(&acc2[l][4 * j + 3], h3);
            if (j == 0) atomicAdd(&gcnt[l], 1);
        } else {
            float inv = 1.0f / cnt[g];
            atomicAdd(&out[g * F_HID + 4 * j + 0], h0 * inv);
            atomicAdd(&out[g * F_HID + 4 * j + 1], h1 * inv);
            atomicAdd(&out[g * F_HID + 4 * j + 2], h2 * inv);
            atomicAdd(&out[g * F_HID + 4 * j + 3], h3 * inv);
        }
    }
    __syncthreads();
    if (t < 8 * F_HID) {
        int l = t >> 4, c = t & 15;
        if (gcnt[l] > 0) {
            float inv = 1.0f / cnt[g0 + l];
            atomicAdd(&out[(g0 + l) * F_HID + c], acc2[l][c] * inv);
        }
    }
}

// ---------------- launcher ----------------

extern "C" void kernel_launch(void* const* d_in, const int* in_sizes, int n_in,
                              void* d_out, int out_size, void* d_ws, size_t ws_size,
                              hipStream_t stream) {
    const float* x     = (const float*)d_in[0];
    const int*   ei    = (const int*)d_in[1];   // [2, N_EDGES]
    const int*   batch = (const int*)d_in[2];
    const float* W1    = (const float*)d_in[3];
    const float* b1    = (const float*)d_in[4];
    const float* W2    = (const float*)d_in[5];
    const float* b2    = (const float*)d_in[6];
    float* out = (float*)d_out;

    int*            cursor = (int*)d_ws;                                   // NBKT*8 (pad 3200)
    unsigned*       packed = (unsigned*)(cursor + 3200);                   // NBKT*CAP
    int2*           rowbc  = (int2*)(packed + (size_t)NBKT * CAP);         // N int2
    int*            col    = (int*)(rowbc + N_NODES);                      // NBKT*CAP
    float*          dinv   = (float*)(col + (size_t)NBKT * CAP);           // N
    unsigned short* pb_a   = (unsigned short*)(dinv + N_NODES);            // (N+1)*16
    unsigned short* pb_b   = pb_a + (size_t)(N_NODES + 1) * F_HID;         // (N+1)*16
    float*          cnt    = (float*)(pb_b + (size_t)(N_NODES + 1) * F_HID); // 512

    const int* src = ei;
    const int* dst = ei + N_EDGES;

    const int nb_pull = (N_NODES * 8) / 256;        // 3125 exactly

    k_zero<<<(N_GRAPHS * F_HID + 255) / 256, 256, 0, stream>>>(cursor, out, cnt,
                                                               pb_a, pb_b);
    k_part<<<NCHUNK, PBLK, 0, stream>>>(src, dst, batch, cursor, packed, cnt);
    k_csr<<<NBKT, 512, 0, stream>>>(cursor, packed, x, W1, rowbc, col, dinv, pb_a);
    k_pull_mid<<<nb_pull, 256, 0, stream>>>(rowbc, col, pb_a, dinv, W2, b1, pb_b);
    k_pull_pool<<<nb_pull, 256, 0, stream>>>(rowbc, col, pb_b, dinv, batch, b2,
                                             cnt, out);
}